// Round 4
// baseline (1090.022 us; speedup 1.0000x reference)
//
#include <hip/hip_runtime.h>
#include <stdint.h>

typedef __bf16 bf16;
typedef __attribute__((ext_vector_type(8))) __bf16 bf16x8;
typedef __attribute__((ext_vector_type(4))) float f32x4;

#define N_NODES 100000
#define F_IN 165

static inline int cdiv(int a, int b) { return (a + b - 1) / b; }

__device__ __forceinline__ float bfu(unsigned hw) {
  union { unsigned u; float f; } v; v.u = hw << 16; return v.f;
}
__device__ __forceinline__ unsigned packbf2(float a, float b) {
  bf16 x = (bf16)a, y = (bf16)b;
  unsigned short sx = __builtin_bit_cast(unsigned short, x);
  unsigned short sy = __builtin_bit_cast(unsigned short, y);
  return (unsigned)sx | ((unsigned)sy << 16);
}

__device__ __forceinline__ void async16(const bf16* g, const bf16* l) {
  __builtin_amdgcn_global_load_lds(
      (const __attribute__((address_space(1))) void*)g,
      (__attribute__((address_space(3))) void*)l, 16, 0, 0);
}

// ---------------- edge dtype detection ----------------
// int64 edges (little-endian): every odd int32 slot is a zero high-word.
__global__ void detect_k(const int* __restrict__ ei32, int* __restrict__ flag) {
  int i = blockIdx.x * 256 + threadIdx.x;  // 65536 samples
  int v = ei32[2 * i + 1];
  if (v != 0) atomicOr(flag, 1);
}

// ---------------- graph preprocessing (sh: 1 = int64-low-words, 0 = int32) ------

__global__ void deg_cnt_k(const int* __restrict__ ei, int E, const int* __restrict__ flag,
                          int* __restrict__ deg, int* __restrict__ cnt) {
  int e = blockIdx.x * 256 + threadIdx.x;
  if (e >= E) return;
  int sh = (*flag) ? 0 : 1;
  int s = ei[(size_t)e << sh];
  int d = ei[(size_t)(E + e) << sh];
  if ((unsigned)s >= (unsigned)N_NODES || (unsigned)d >= (unsigned)N_NODES) return;
  if (s != d) { atomicAdd(deg + s, 1); atomicAdd(cnt + d, 1); }
}

__global__ void dinv_k(const int* __restrict__ deg, float* __restrict__ dinv, int n) {
  int i = blockIdx.x * 256 + threadIdx.x;
  if (i >= n) return;
  int dg = deg[i];
  dinv[i] = dg > 0 ? rsqrtf((float)dg) : 0.f;
}

__global__ void scanA_k(const int* __restrict__ cnt, int* __restrict__ bsum, int nElem) {
  __shared__ int s[256];
  int b = blockIdx.x, t = threadIdx.x;
  int base = b * 1024;
  int sum = 0;
  for (int i = t; i < 1024; i += 256) {
    int idx = base + i;
    sum += (idx < nElem) ? cnt[idx] : 0;
  }
  s[t] = sum; __syncthreads();
  for (int off = 128; off > 0; off >>= 1) {
    if (t < off) s[t] += s[t + off];
    __syncthreads();
  }
  if (t == 0) bsum[b] = s[0];
}

__global__ void scanB_k(int* __restrict__ bsum, int* __restrict__ rowptrN, int nChunk) {
  __shared__ int s[128];
  int t = threadIdx.x;
  int v = (t < nChunk) ? bsum[t] : 0;
  s[t] = v; __syncthreads();
  for (int off = 1; off < 128; off <<= 1) {
    int x = (t >= off) ? s[t - off] : 0;
    __syncthreads();
    s[t] += x;
    __syncthreads();
  }
  int excl = s[t] - v;
  if (t < nChunk) bsum[t] = excl;
  if (t == 127) *rowptrN = s[127];
}

__global__ void scanC_k(const int* __restrict__ cnt, const int* __restrict__ bsum,
                        int* __restrict__ rowptr, int nElem) {
  __shared__ int s[256];
  int b = blockIdx.x, t = threadIdx.x;
  int base = b * 1024 + t * 4;
  int v[4]; int tot = 0;
  for (int i = 0; i < 4; i++) {
    int idx = base + i;
    v[i] = (idx < nElem) ? cnt[idx] : 0;
    tot += v[i];
  }
  s[t] = tot; __syncthreads();
  for (int off = 1; off < 256; off <<= 1) {
    int x = (t >= off) ? s[t - off] : 0;
    __syncthreads();
    s[t] += x;
    __syncthreads();
  }
  int excl = s[t] - tot + bsum[b];
  for (int i = 0; i < 4; i++) {
    int idx = base + i;
    if (idx < nElem) { rowptr[idx] = excl; excl += v[i]; }
  }
}

__global__ void fill_k(const int* __restrict__ ei, int E, const int* __restrict__ flag,
                       const float* __restrict__ dinv, const int* __restrict__ rowptr,
                       int* __restrict__ fillc, int2* __restrict__ csr) {
  int e = blockIdx.x * 256 + threadIdx.x;
  if (e >= E) return;
  int sh = (*flag) ? 0 : 1;
  int s = ei[(size_t)e << sh];
  int d = ei[(size_t)(E + e) << sh];
  if ((unsigned)s >= (unsigned)N_NODES || (unsigned)d >= (unsigned)N_NODES) return;
  if (s == d) return;
  int pos = rowptr[d] + atomicAdd(fillc + d, 1);
  float w = -dinv[s] * dinv[d];
  csr[pos] = make_int2(s, __builtin_bit_cast(int, w));
}

// ---------------- weight prep ----------------

// W (float): [3][Fin][128].  out (bf16): [384][Kp] = (W0-W2)^T | W1^T | (2W2)^T
__global__ void build_wct_k(const float* __restrict__ W, bf16* __restrict__ out, int Fin, int Kp) {
  int idx = blockIdx.x * 256 + threadIdx.x;
  if (idx >= 384 * Kp) return;
  int r = idx / Kp, k = idx % Kp;
  int t = r >> 7, j = r & 127;
  float v = 0.f;
  if (k < Fin) {
    if (t == 0)
      v = W[(size_t)k * 128 + j] - W[(size_t)2 * Fin * 128 + (size_t)k * 128 + j];
    else if (t == 1)
      v = W[(size_t)Fin * 128 + (size_t)k * 128 + j];
    else
      v = 2.f * W[(size_t)2 * Fin * 128 + (size_t)k * 128 + j];
  }
  out[(size_t)r * Kp + k] = (bf16)v;
}

// pad x (float [N][165]) -> xp (bf16 [N][192], zeros in 165..191)
__global__ void pad_x_k(const float* __restrict__ x, bf16* __restrict__ xp) {
  int idx = blockIdx.x * 256 + threadIdx.x;
  if (idx >= N_NODES * 192) return;
  int n = idx / 192, k = idx % 192;
  xp[idx] = (k < F_IN) ? (bf16)x[(size_t)n * F_IN + k] : (bf16)0.f;
}

// ---------------- GEMM: C[M][128] = A[M][lda] @ Bt[128][K]^T ----------------

__global__ __launch_bounds__(256) void gemm_bt_k(const bf16* __restrict__ A, int lda,
                                                 const bf16* __restrict__ Bt, int K,
                                                 bf16* __restrict__ C, int M) {
  __shared__ __align__(16) bf16 As[128 * 32];
  __shared__ __align__(16) bf16 Bs[128 * 32];
  const int tid = threadIdx.x;
  const int w = tid >> 6, l = tid & 63;
  const int mBase = blockIdx.x * 128;
  const int wm = (w >> 1) * 64, wn = (w & 1) * 64;
  const int lr = l & 15, lq = l >> 4;
  f32x4 acc[4][4] = {};
  for (int k0 = 0; k0 < K; k0 += 32) {
#pragma unroll
    for (int p = 0; p < 2; ++p) {
      int q = w * 2 + p;
      int row = q * 16 + (l >> 2);
      int seg = (l & 3) * 8;
      int ar = mBase + row; if (ar > M - 1) ar = M - 1;  // clamp: no OOB reads
      async16(A + (size_t)ar * lda + k0 + seg, &As[q * 512]);
      async16(Bt + (size_t)row * K + k0 + seg, &Bs[q * 512]);
    }
    __syncthreads();
    bf16x8 a[4], b[4];
#pragma unroll
    for (int i = 0; i < 4; i++) a[i] = *(const bf16x8*)&As[(wm + i * 16 + lr) * 32 + lq * 8];
#pragma unroll
    for (int j = 0; j < 4; j++) b[j] = *(const bf16x8*)&Bs[(wn + j * 16 + lr) * 32 + lq * 8];
#pragma unroll
    for (int i = 0; i < 4; i++)
#pragma unroll
      for (int j = 0; j < 4; j++)
        acc[i][j] = __builtin_amdgcn_mfma_f32_16x16x32_bf16(a[i], b[j], acc[i][j], 0, 0, 0);
    __syncthreads();
  }
#pragma unroll
  for (int i = 0; i < 4; i++) {
#pragma unroll
    for (int r = 0; r < 4; r++) {
      int row = mBase + wm + i * 16 + lq * 4 + r;
      if (row < M) {
#pragma unroll
        for (int j = 0; j < 4; j++) {
          int col = wn + j * 16 + lr;
          C[(size_t)row * 128 + col] = (bf16)acc[i][j][r];
        }
      }
    }
  }
}

// ---------------- sparse propagation ----------------
// One wave per node; lane c handles feature pair (2c, 2c+1). All strides 128.
// MODE 0: out[n] = P(gsrc)[n] + addA[n]                        (bf16)
// MODE 1: out[n] = relu(P(gsrc)[n] + addA[n] + bias)           (bf16)
// MODE 2: v = P(gsrc)[n] + addA[n] + addB[n] + bias;
//         fout[n*2..] = log_softmax(v @ Wl + bl)               (FLOAT32 out)
template <int MODE>
__global__ __launch_bounds__(256) void prop_k(const int* __restrict__ rowptr,
                                              const int2* __restrict__ csr,
                                              const bf16* __restrict__ gsrc,
                                              const bf16* __restrict__ addA,
                                              const bf16* __restrict__ addB,
                                              const float* __restrict__ bias,
                                              const float* __restrict__ Wl,
                                              const float* __restrict__ bl,
                                              bf16* __restrict__ out,
                                              float* __restrict__ fout) {
  int n = blockIdx.x * 4 + (threadIdx.x >> 6);
  int c = threadIdx.x & 63;
  int beg = rowptr[n], end = rowptr[n + 1];
  float a0 = 0.f, a1 = 0.f;
  for (int e = beg; e < end; ++e) {
    int2 sw = csr[e];
    float w = __builtin_bit_cast(float, sw.y);
    unsigned u = *(const unsigned*)(gsrc + (size_t)sw.x * 128 + 2 * c);
    a0 += w * bfu(u & 0xffffu);
    a1 += w * bfu(u >> 16);
  }
  unsigned ua = *(const unsigned*)(addA + (size_t)n * 128 + 2 * c);
  a0 += bfu(ua & 0xffffu);
  a1 += bfu(ua >> 16);
  if (MODE == 0) {
    *(unsigned*)(out + (size_t)n * 128 + 2 * c) = packbf2(a0, a1);
  } else if (MODE == 1) {
    a0 = fmaxf(a0 + bias[2 * c], 0.f);
    a1 = fmaxf(a1 + bias[2 * c + 1], 0.f);
    *(unsigned*)(out + (size_t)n * 128 + 2 * c) = packbf2(a0, a1);
  } else {
    unsigned uh = *(const unsigned*)(addB + (size_t)n * 128 + 2 * c);
    a0 += bfu(uh & 0xffffu) + bias[2 * c];
    a1 += bfu(uh >> 16) + bias[2 * c + 1];
    float z0 = a0 * Wl[(2 * c) * 2 + 0] + a1 * Wl[(2 * c + 1) * 2 + 0];
    float z1 = a0 * Wl[(2 * c) * 2 + 1] + a1 * Wl[(2 * c + 1) * 2 + 1];
    for (int off = 32; off > 0; off >>= 1) {
      z0 += __shfl_down(z0, off);
      z1 += __shfl_down(z1, off);
    }
    if (c == 0) {
      z0 += bl[0];
      z1 += bl[1];
      float m = fmaxf(z0, z1);
      float lse = m + logf(expf(z0 - m) + expf(z1 - m));
      fout[(size_t)n * 2 + 0] = z0 - lse;   // float32 logits
      fout[(size_t)n * 2 + 1] = z1 - lse;
    }
  }
}

// edges -> float32 output region
__global__ void copy_edges_k(const int* __restrict__ ei, const int* __restrict__ flag,
                             float* __restrict__ out, int n) {
  int i = blockIdx.x * 256 + threadIdx.x;
  if (i >= n) return;
  int sh = (*flag) ? 0 : 1;
  out[i] = (float)ei[(size_t)i << sh];
}

// ---------------- launch ----------------

extern "C" void kernel_launch(void* const* d_in, const int* in_sizes, int n_in,
                              void* d_out, int out_size, void* d_ws, size_t ws_size,
                              hipStream_t stream) {
  const float* x = (const float*)d_in[0];
  const int* ei = (const int*)d_in[1];
  const float* W1 = (const float*)d_in[2];
  const float* b1 = (const float*)d_in[3];
  const float* W2 = (const float*)d_in[4];
  const float* b2 = (const float*)d_in[5];
  const float* Wl = (const float*)d_in[6];
  const float* bl = (const float*)d_in[7];
  float* outp = (float*)d_out;   // d_out is FLOAT32 (reference output dtype)

  const int N = N_NODES;
  const int E = in_sizes[1] / 2;
  const int nChunk = cdiv(N, 1024);  // 98

  char* ws = (char*)d_ws;
  size_t off = 0;
  auto alloc = [&](size_t bytes) {
    off = (off + 255) & ~(size_t)255;
    size_t o = off;
    off += bytes;
    return o;
  };
  size_t o_z = alloc((size_t)(3 * N + 1) * 4);  // deg | cnt | fillc | flag — one memset
  int* deg = (int*)(ws + o_z);
  int* cnt = deg + N;
  int* fillc = cnt + N;
  int* flag = fillc + N;
  int* rowptr = (int*)(ws + alloc((size_t)(N + 1) * 4));
  int* bsum = (int*)(ws + alloc(512));
  float* dinv = (float*)(ws + alloc((size_t)N * 4));
  int2* csr = (int2*)(ws + alloc((size_t)E * 8));
  bf16* wct1 = (bf16*)(ws + alloc((size_t)384 * 192 * 2));
  bf16* wct2 = (bf16*)(ws + alloc((size_t)384 * 128 * 2));
  bf16* xp = (bf16*)(ws + alloc((size_t)N * 192 * 2));  // X0 = first N*128 of this
  bf16* X0 = xp;
  bf16* B1 = (bf16*)(ws + alloc((size_t)N * 128 * 2));
  bf16* B2 = (bf16*)(ws + alloc((size_t)N * 128 * 2));
  (void)ws_size;  // total ≈ 105 MB

  hipMemsetAsync(deg, 0, (size_t)(3 * N + 1) * 4, stream);

  detect_k<<<256, 256, 0, stream>>>(ei, flag);
  deg_cnt_k<<<cdiv(E, 256), 256, 0, stream>>>(ei, E, flag, deg, cnt);
  dinv_k<<<cdiv(N, 256), 256, 0, stream>>>(deg, dinv, N);
  scanA_k<<<nChunk, 256, 0, stream>>>(cnt, bsum, N);
  scanB_k<<<1, 128, 0, stream>>>(bsum, rowptr + N, nChunk);
  scanC_k<<<nChunk, 256, 0, stream>>>(cnt, bsum, rowptr, N);
  fill_k<<<cdiv(E, 256), 256, 0, stream>>>(ei, E, flag, dinv, rowptr, fillc, csr);

  pad_x_k<<<cdiv(N * 192, 256), 256, 0, stream>>>(x, xp);
  build_wct_k<<<cdiv(384 * 192, 256), 256, 0, stream>>>(W1, wct1, F_IN, 192);
  build_wct_k<<<cdiv(384 * 128, 256), 256, 0, stream>>>(W2, wct2, 128, 128);

  const int gm = cdiv(N, 128);
  // ----- layer 1: Y0=x(W0-W2), Y1=xW1, Y2=x(2W2) -----
  gemm_bt_k<<<gm, 256, 0, stream>>>(xp, 192, wct1 + 128 * 192, 192, B2, N);  // Y1 -> B2
  gemm_bt_k<<<gm, 256, 0, stream>>>(xp, 192, wct1 + 256 * 192, 192, B1, N);  // Y2 -> B1
  // A1 = P(Y2) + Y1  (gather B1, own-row B2 -> B2)
  prop_k<0><<<N / 4, 256, 0, stream>>>(rowptr, csr, B1, B2, nullptr, nullptr, nullptr, nullptr, B2, nullptr);
  gemm_bt_k<<<gm, 256, 0, stream>>>(xp, 192, wct1, 192, B1, N);              // Y0 -> B1
  // h = relu(P(A1) + Y0 + b1)  (gather B2, own-row B1 -> B1)
  prop_k<1><<<N / 4, 256, 0, stream>>>(rowptr, csr, B2, B1, nullptr, b1, nullptr, nullptr, B1, nullptr);
  // ----- layer 2: Z0=h(W0-W2), Z1=hW1, Z2=h(2W2);  h lives in B1 -----
  gemm_bt_k<<<gm, 256, 0, stream>>>(B1, 128, wct2 + 128 * 128, 128, X0, N);  // Z1 -> X0
  gemm_bt_k<<<gm, 256, 0, stream>>>(B1, 128, wct2 + 256 * 128, 128, B2, N);  // Z2 -> B2
  // A2 = P(Z2) + Z1  (gather B2, own-row X0 -> X0)
  prop_k<0><<<N / 4, 256, 0, stream>>>(rowptr, csr, B2, X0, nullptr, nullptr, nullptr, nullptr, X0, nullptr);
  gemm_bt_k<<<gm, 256, 0, stream>>>(B1, 128, wct2, 128, B2, N);              // Z0 -> B2
  // logits(float32) = log_softmax((P(A2) + Z0 + h + b2) @ Wl + bl) -> outp[0:2N)
  prop_k<2><<<N / 4, 256, 0, stream>>>(rowptr, csr, X0, B2, B1, b2, Wl, bl, nullptr, outp);

  // edges (float32) -> outp[2N : 2N+2E)
  copy_edges_k<<<cdiv(2 * E, 256), 256, 0, stream>>>(ei, flag, outp + (size_t)2 * N, 2 * E);
}

// Round 5
// 735.858 us; speedup vs baseline: 1.4813x; 1.4813x over previous
//
#include <hip/hip_runtime.h>
#include <stdint.h>

typedef __bf16 bf16;
typedef __attribute__((ext_vector_type(8))) __bf16 bf16x8;
typedef __attribute__((ext_vector_type(4))) float f32x4;

#define N_NODES 100000
#define F_IN 165

static inline int cdiv(int a, int b) { return (a + b - 1) / b; }

__device__ __forceinline__ float bfu(unsigned hw) {
  union { unsigned u; float f; } v; v.u = hw << 16; return v.f;
}
__device__ __forceinline__ unsigned packbf2(float a, float b) {
  bf16 x = (bf16)a, y = (bf16)b;
  unsigned short sx = __builtin_bit_cast(unsigned short, x);
  unsigned short sy = __builtin_bit_cast(unsigned short, y);
  return (unsigned)sx | ((unsigned)sy << 16);
}

__device__ __forceinline__ void async16(const bf16* g, const bf16* l) {
  __builtin_amdgcn_global_load_lds(
      (const __attribute__((address_space(1))) void*)g,
      (__attribute__((address_space(3))) void*)l, 16, 0, 0);
}

// ---------------- edge dtype detection ----------------
// int64 edges (little-endian): every odd int32 slot is a zero high-word.
__global__ void detect_k(const int* __restrict__ ei32, int* __restrict__ flag) {
  int i = blockIdx.x * 256 + threadIdx.x;  // 65536 samples
  int v = ei32[2 * i + 1];
  if (v != 0) atomicOr(flag, 1);
}

// ---------------- graph preprocessing (sh: 1 = int64-low-words, 0 = int32) ------

__global__ void deg_cnt_k(const int* __restrict__ ei, int E, const int* __restrict__ flag,
                          int* __restrict__ deg, int* __restrict__ cnt) {
  int e = blockIdx.x * 256 + threadIdx.x;
  if (e >= E) return;
  int sh = (*flag) ? 0 : 1;
  int s = ei[(size_t)e << sh];
  int d = ei[(size_t)(E + e) << sh];
  if ((unsigned)s >= (unsigned)N_NODES || (unsigned)d >= (unsigned)N_NODES) return;
  if (s != d) { atomicAdd(deg + s, 1); atomicAdd(cnt + d, 1); }
}

__global__ void dinv_k(const int* __restrict__ deg, float* __restrict__ dinv, int n) {
  int i = blockIdx.x * 256 + threadIdx.x;
  if (i >= n) return;
  int dg = deg[i];
  dinv[i] = dg > 0 ? rsqrtf((float)dg) : 0.f;
}

__global__ void scanA_k(const int* __restrict__ cnt, int* __restrict__ bsum, int nElem) {
  __shared__ int s[256];
  int b = blockIdx.x, t = threadIdx.x;
  int base = b * 1024;
  int sum = 0;
  for (int i = t; i < 1024; i += 256) {
    int idx = base + i;
    sum += (idx < nElem) ? cnt[idx] : 0;
  }
  s[t] = sum; __syncthreads();
  for (int off = 128; off > 0; off >>= 1) {
    if (t < off) s[t] += s[t + off];
    __syncthreads();
  }
  if (t == 0) bsum[b] = s[0];
}

__global__ void scanB_k(int* __restrict__ bsum, int* __restrict__ rowptrN, int nChunk) {
  __shared__ int s[128];
  int t = threadIdx.x;
  int v = (t < nChunk) ? bsum[t] : 0;
  s[t] = v; __syncthreads();
  for (int off = 1; off < 128; off <<= 1) {
    int x = (t >= off) ? s[t - off] : 0;
    __syncthreads();
    s[t] += x;
    __syncthreads();
  }
  int excl = s[t] - v;
  if (t < nChunk) bsum[t] = excl;
  if (t == 127) *rowptrN = s[127];
}

__global__ void scanC_k(const int* __restrict__ cnt, const int* __restrict__ bsum,
                        int* __restrict__ rowptr, int nElem) {
  __shared__ int s[256];
  int b = blockIdx.x, t = threadIdx.x;
  int base = b * 1024 + t * 4;
  int v[4]; int tot = 0;
  for (int i = 0; i < 4; i++) {
    int idx = base + i;
    v[i] = (idx < nElem) ? cnt[idx] : 0;
    tot += v[i];
  }
  s[t] = tot; __syncthreads();
  for (int off = 1; off < 256; off <<= 1) {
    int x = (t >= off) ? s[t - off] : 0;
    __syncthreads();
    s[t] += x;
    __syncthreads();
  }
  int excl = s[t] - tot + bsum[b];
  for (int i = 0; i < 4; i++) {
    int idx = base + i;
    if (idx < nElem) { rowptr[idx] = excl; excl += v[i]; }
  }
}

__global__ void fill_k(const int* __restrict__ ei, int E, const int* __restrict__ flag,
                       const float* __restrict__ dinv, const int* __restrict__ rowptr,
                       int* __restrict__ fillc, int2* __restrict__ csr) {
  int e = blockIdx.x * 256 + threadIdx.x;
  if (e >= E) return;
  int sh = (*flag) ? 0 : 1;
  int s = ei[(size_t)e << sh];
  int d = ei[(size_t)(E + e) << sh];
  if ((unsigned)s >= (unsigned)N_NODES || (unsigned)d >= (unsigned)N_NODES) return;
  if (s == d) return;
  int pos = rowptr[d] + atomicAdd(fillc + d, 1);
  float w = -dinv[s] * dinv[d];
  csr[pos] = make_int2(s, __builtin_bit_cast(int, w));
}

// ---------------- weight prep ----------------

// W (float): [3][Fin][128].  out (bf16): [384][Kp] = (W0-W2)^T | W1^T | (2W2)^T
__global__ void build_wct_k(const float* __restrict__ W, bf16* __restrict__ out, int Fin, int Kp) {
  int idx = blockIdx.x * 256 + threadIdx.x;
  if (idx >= 384 * Kp) return;
  int r = idx / Kp, k = idx % Kp;
  int t = r >> 7, j = r & 127;
  float v = 0.f;
  if (k < Fin) {
    if (t == 0)
      v = W[(size_t)k * 128 + j] - W[(size_t)2 * Fin * 128 + (size_t)k * 128 + j];
    else if (t == 1)
      v = W[(size_t)Fin * 128 + (size_t)k * 128 + j];
    else
      v = 2.f * W[(size_t)2 * Fin * 128 + (size_t)k * 128 + j];
  }
  out[(size_t)r * Kp + k] = (bf16)v;
}

// pad x (float [N][165]) -> xp (bf16 [N][192], zeros in 165..191)
__global__ void pad_x_k(const float* __restrict__ x, bf16* __restrict__ xp) {
  int idx = blockIdx.x * 256 + threadIdx.x;
  if (idx >= N_NODES * 192) return;
  int n = idx / 192, k = idx % 192;
  xp[idx] = (k < F_IN) ? (bf16)x[(size_t)n * F_IN + k] : (bf16)0.f;
}

// ---------------- GEMM: C[M][128] = A[M][lda] @ Bt[128][K]^T ----------------

__global__ __launch_bounds__(256) void gemm_bt_k(const bf16* __restrict__ A, int lda,
                                                 const bf16* __restrict__ Bt, int K,
                                                 bf16* __restrict__ C, int M) {
  __shared__ __align__(16) bf16 As[128 * 32];
  __shared__ __align__(16) bf16 Bs[128 * 32];
  const int tid = threadIdx.x;
  const int w = tid >> 6, l = tid & 63;
  const int mBase = blockIdx.x * 128;
  const int wm = (w >> 1) * 64, wn = (w & 1) * 64;
  const int lr = l & 15, lq = l >> 4;
  f32x4 acc[4][4] = {};
  for (int k0 = 0; k0 < K; k0 += 32) {
#pragma unroll
    for (int p = 0; p < 2; ++p) {
      int q = w * 2 + p;
      int row = q * 16 + (l >> 2);
      int seg = (l & 3) * 8;
      int ar = mBase + row; if (ar > M - 1) ar = M - 1;  // clamp: no OOB reads
      async16(A + (size_t)ar * lda + k0 + seg, &As[q * 512]);
      async16(Bt + (size_t)row * K + k0 + seg, &Bs[q * 512]);
    }
    __syncthreads();
    bf16x8 a[4], b[4];
#pragma unroll
    for (int i = 0; i < 4; i++) a[i] = *(const bf16x8*)&As[(wm + i * 16 + lr) * 32 + lq * 8];
#pragma unroll
    for (int j = 0; j < 4; j++) b[j] = *(const bf16x8*)&Bs[(wn + j * 16 + lr) * 32 + lq * 8];
#pragma unroll
    for (int i = 0; i < 4; i++)
#pragma unroll
      for (int j = 0; j < 4; j++)
        acc[i][j] = __builtin_amdgcn_mfma_f32_16x16x32_bf16(a[i], b[j], acc[i][j], 0, 0, 0);
    __syncthreads();
  }
#pragma unroll
  for (int i = 0; i < 4; i++) {
#pragma unroll
    for (int r = 0; r < 4; r++) {
      int row = mBase + wm + i * 16 + lq * 4 + r;
      if (row < M) {
#pragma unroll
        for (int j = 0; j < 4; j++) {
          int col = wn + j * 16 + lr;
          C[(size_t)row * 128 + col] = (bf16)acc[i][j][r];
        }
      }
    }
  }
}

// ---------------- sparse propagation (latency-optimized) ----------------
// One wave per node. Half-wave per edge: lanes 0-31 edge e, lanes 32-63 edge e+1.
// Each lane covers 4 features (lc*4..lc*4+3) via one dwordx2 gather.
// Loop body handles 8 edges (4 per half) -> 4 csr loads + 4 gathers in flight.
// MODE 0: out[n] = P(gsrc)[n] + addA[n]                        (bf16)
// MODE 1: out[n] = relu(P(gsrc)[n] + addA[n] + bias)           (bf16)
// MODE 2: v = P(gsrc)[n] + addA[n] + addB[n] + bias;
//         fout[n*2..] = log_softmax(v @ Wl + bl)               (float32)
template <int MODE>
__global__ __launch_bounds__(256) void prop_k(const int* __restrict__ rowptr,
                                              const int2* __restrict__ csr,
                                              const bf16* __restrict__ gsrc,
                                              const bf16* __restrict__ addA,
                                              const bf16* __restrict__ addB,
                                              const float* __restrict__ bias,
                                              const float* __restrict__ Wl,
                                              const float* __restrict__ bl,
                                              bf16* __restrict__ out,
                                              float* __restrict__ fout) {
  const int n = blockIdx.x * 4 + (threadIdx.x >> 6);
  const int c = threadIdx.x & 63;
  const int half = c >> 5, lc = c & 31;
  const int beg = rowptr[n], end = rowptr[n + 1];
  const bf16* __restrict__ gl = gsrc + lc * 4;  // lane-fixed feature offset

  float a0 = 0.f, a1 = 0.f, a2 = 0.f, a3 = 0.f;
  for (int e0 = beg; e0 < end; e0 += 8) {
    int2 sw[4];
    float wv[4];
    uint2 g[4];
#pragma unroll
    for (int k = 0; k < 4; k++) {
      int idx = e0 + 2 * k + half;
      bool valid = idx < end;
      sw[k] = csr[valid ? idx : beg];
      wv[k] = valid ? __builtin_bit_cast(float, sw[k].y) : 0.f;
    }
#pragma unroll
    for (int k = 0; k < 4; k++) g[k] = *(const uint2*)(gl + (size_t)sw[k].x * 128);
#pragma unroll
    for (int k = 0; k < 4; k++) {
      a0 += wv[k] * bfu(g[k].x & 0xffffu);
      a1 += wv[k] * bfu(g[k].x >> 16);
      a2 += wv[k] * bfu(g[k].y & 0xffffu);
      a3 += wv[k] * bfu(g[k].y >> 16);
    }
  }

  if (MODE == 2) {
    // add per-node terms once (half 0 only); @Wl reduction is linear over lanes
    if (half == 0) {
      uint2 ua = *(const uint2*)(addA + (size_t)n * 128 + lc * 4);
      uint2 uh = *(const uint2*)(addB + (size_t)n * 128 + lc * 4);
      a0 += bfu(ua.x & 0xffffu) + bfu(uh.x & 0xffffu) + bias[4 * lc + 0];
      a1 += bfu(ua.x >> 16) + bfu(uh.x >> 16) + bias[4 * lc + 1];
      a2 += bfu(ua.y & 0xffffu) + bfu(uh.y & 0xffffu) + bias[4 * lc + 2];
      a3 += bfu(ua.y >> 16) + bfu(uh.y >> 16) + bias[4 * lc + 3];
    }
    float z0 = a0 * Wl[(4 * lc + 0) * 2] + a1 * Wl[(4 * lc + 1) * 2] +
               a2 * Wl[(4 * lc + 2) * 2] + a3 * Wl[(4 * lc + 3) * 2];
    float z1 = a0 * Wl[(4 * lc + 0) * 2 + 1] + a1 * Wl[(4 * lc + 1) * 2 + 1] +
               a2 * Wl[(4 * lc + 2) * 2 + 1] + a3 * Wl[(4 * lc + 3) * 2 + 1];
#pragma unroll
    for (int off = 32; off > 0; off >>= 1) {
      z0 += __shfl_down(z0, off);
      z1 += __shfl_down(z1, off);
    }
    if (c == 0) {
      z0 += bl[0];
      z1 += bl[1];
      float m = fmaxf(z0, z1);
      float lse = m + logf(expf(z0 - m) + expf(z1 - m));
      fout[(size_t)n * 2 + 0] = z0 - lse;
      fout[(size_t)n * 2 + 1] = z1 - lse;
    }
  } else {
    // merge halves: lanes 0..31 receive partials from lanes 32..63
    a0 += __shfl_down(a0, 32);
    a1 += __shfl_down(a1, 32);
    a2 += __shfl_down(a2, 32);
    a3 += __shfl_down(a3, 32);
    if (half == 0) {
      uint2 ua = *(const uint2*)(addA + (size_t)n * 128 + lc * 4);
      a0 += bfu(ua.x & 0xffffu);
      a1 += bfu(ua.x >> 16);
      a2 += bfu(ua.y & 0xffffu);
      a3 += bfu(ua.y >> 16);
      if (MODE == 1) {
        a0 = fmaxf(a0 + bias[4 * lc + 0], 0.f);
        a1 = fmaxf(a1 + bias[4 * lc + 1], 0.f);
        a2 = fmaxf(a2 + bias[4 * lc + 2], 0.f);
        a3 = fmaxf(a3 + bias[4 * lc + 3], 0.f);
      }
      uint2 st;
      st.x = packbf2(a0, a1);
      st.y = packbf2(a2, a3);
      *(uint2*)(out + (size_t)n * 128 + lc * 4) = st;
    }
  }
}

// edges -> float32 output region
__global__ void copy_edges_k(const int* __restrict__ ei, const int* __restrict__ flag,
                             float* __restrict__ out, int n) {
  int i = blockIdx.x * 256 + threadIdx.x;
  if (i >= n) return;
  int sh = (*flag) ? 0 : 1;
  out[i] = (float)ei[(size_t)i << sh];
}

// ---------------- launch ----------------

extern "C" void kernel_launch(void* const* d_in, const int* in_sizes, int n_in,
                              void* d_out, int out_size, void* d_ws, size_t ws_size,
                              hipStream_t stream) {
  const float* x = (const float*)d_in[0];
  const int* ei = (const int*)d_in[1];
  const float* W1 = (const float*)d_in[2];
  const float* b1 = (const float*)d_in[3];
  const float* W2 = (const float*)d_in[4];
  const float* b2 = (const float*)d_in[5];
  const float* Wl = (const float*)d_in[6];
  const float* bl = (const float*)d_in[7];
  float* outp = (float*)d_out;   // d_out is FLOAT32 (reference output dtype)

  const int N = N_NODES;
  const int E = in_sizes[1] / 2;
  const int nChunk = cdiv(N, 1024);  // 98

  char* ws = (char*)d_ws;
  size_t off = 0;
  auto alloc = [&](size_t bytes) {
    off = (off + 255) & ~(size_t)255;
    size_t o = off;
    off += bytes;
    return o;
  };
  size_t o_z = alloc((size_t)(3 * N + 1) * 4);  // deg | cnt | fillc | flag — one memset
  int* deg = (int*)(ws + o_z);
  int* cnt = deg + N;
  int* fillc = cnt + N;
  int* flag = fillc + N;
  int* rowptr = (int*)(ws + alloc((size_t)(N + 1) * 4));
  int* bsum = (int*)(ws + alloc(512));
  float* dinv = (float*)(ws + alloc((size_t)N * 4));
  int2* csr = (int2*)(ws + alloc((size_t)E * 8));
  bf16* wct1 = (bf16*)(ws + alloc((size_t)384 * 192 * 2));
  bf16* wct2 = (bf16*)(ws + alloc((size_t)384 * 128 * 2));
  bf16* xp = (bf16*)(ws + alloc((size_t)N * 192 * 2));  // X0 = first N*128 of this
  bf16* X0 = xp;
  bf16* B1 = (bf16*)(ws + alloc((size_t)N * 128 * 2));
  bf16* B2 = (bf16*)(ws + alloc((size_t)N * 128 * 2));
  (void)ws_size;  // total ≈ 105 MB

  hipMemsetAsync(deg, 0, (size_t)(3 * N + 1) * 4, stream);

  detect_k<<<256, 256, 0, stream>>>(ei, flag);
  deg_cnt_k<<<cdiv(E, 256), 256, 0, stream>>>(ei, E, flag, deg, cnt);
  dinv_k<<<cdiv(N, 256), 256, 0, stream>>>(deg, dinv, N);
  scanA_k<<<nChunk, 256, 0, stream>>>(cnt, bsum, N);
  scanB_k<<<1, 128, 0, stream>>>(bsum, rowptr + N, nChunk);
  scanC_k<<<nChunk, 256, 0, stream>>>(cnt, bsum, rowptr, N);
  fill_k<<<cdiv(E, 256), 256, 0, stream>>>(ei, E, flag, dinv, rowptr, fillc, csr);

  pad_x_k<<<cdiv(N * 192, 256), 256, 0, stream>>>(x, xp);
  build_wct_k<<<cdiv(384 * 192, 256), 256, 0, stream>>>(W1, wct1, F_IN, 192);
  build_wct_k<<<cdiv(384 * 128, 256), 256, 0, stream>>>(W2, wct2, 128, 128);

  const int gm = cdiv(N, 128);
  // ----- layer 1: Y0=x(W0-W2), Y1=xW1, Y2=x(2W2) -----
  gemm_bt_k<<<gm, 256, 0, stream>>>(xp, 192, wct1 + 128 * 192, 192, B2, N);  // Y1 -> B2
  gemm_bt_k<<<gm, 256, 0, stream>>>(xp, 192, wct1 + 256 * 192, 192, B1, N);  // Y2 -> B1
  // A1 = P(Y2) + Y1  (gather B1, own-row B2 -> B2)
  prop_k<0><<<N / 4, 256, 0, stream>>>(rowptr, csr, B1, B2, nullptr, nullptr, nullptr, nullptr, B2, nullptr);
  gemm_bt_k<<<gm, 256, 0, stream>>>(xp, 192, wct1, 192, B1, N);              // Y0 -> B1
  // h = relu(P(A1) + Y0 + b1)  (gather B2, own-row B1 -> B1)
  prop_k<1><<<N / 4, 256, 0, stream>>>(rowptr, csr, B2, B1, nullptr, b1, nullptr, nullptr, B1, nullptr);
  // ----- layer 2: Z0=h(W0-W2), Z1=hW1, Z2=h(2W2);  h lives in B1 -----
  gemm_bt_k<<<gm, 256, 0, stream>>>(B1, 128, wct2 + 128 * 128, 128, X0, N);  // Z1 -> X0
  gemm_bt_k<<<gm, 256, 0, stream>>>(B1, 128, wct2 + 256 * 128, 128, B2, N);  // Z2 -> B2
  // A2 = P(Z2) + Z1  (gather B2, own-row X0 -> X0)
  prop_k<0><<<N / 4, 256, 0, stream>>>(rowptr, csr, B2, X0, nullptr, nullptr, nullptr, nullptr, X0, nullptr);
  gemm_bt_k<<<gm, 256, 0, stream>>>(B1, 128, wct2, 128, B2, N);              // Z0 -> B2
  // logits(float32) = log_softmax((P(A2) + Z0 + h + b2) @ Wl + bl) -> outp[0:2N)
  prop_k<2><<<N / 4, 256, 0, stream>>>(rowptr, csr, X0, B2, B1, b2, Wl, bl, nullptr, outp);

  // edges (float32) -> outp[2N : 2N+2E)
  copy_edges_k<<<cdiv(2 * E, 256), 256, 0, stream>>>(ei, flag, outp + (size_t)2 * N, 2 * E);
}

// Round 6
// 687.965 us; speedup vs baseline: 1.5844x; 1.0696x over previous
//
#include <hip/hip_runtime.h>
#include <stdint.h>

typedef __bf16 bf16;
typedef __attribute__((ext_vector_type(8))) __bf16 bf16x8;
typedef __attribute__((ext_vector_type(4))) float f32x4;

#define N_NODES 100000
#define F_IN 165

static inline int cdiv(int a, int b) { return (a + b - 1) / b; }

__device__ __forceinline__ float bfu(unsigned hw) {
  union { unsigned u; float f; } v; v.u = hw << 16; return v.f;
}
__device__ __forceinline__ unsigned packbf2(float a, float b) {
  bf16 x = (bf16)a, y = (bf16)b;
  unsigned short sx = __builtin_bit_cast(unsigned short, x);
  unsigned short sy = __builtin_bit_cast(unsigned short, y);
  return (unsigned)sx | ((unsigned)sy << 16);
}

__device__ __forceinline__ void async16(const bf16* g, const bf16* l) {
  __builtin_amdgcn_global_load_lds(
      (const __attribute__((address_space(1))) void*)g,
      (__attribute__((address_space(3))) void*)l, 16, 0, 0);
}

// ---------------- edge dtype detection ----------------
__global__ void detect_k(const int* __restrict__ ei32, int* __restrict__ flag) {
  int i = blockIdx.x * 256 + threadIdx.x;  // 65536 samples
  int v = ei32[2 * i + 1];
  if (v != 0) atomicOr(flag, 1);
}

// ---------------- preprocessing (sh: 1 = int64-low-words, 0 = int32) ------
// K1: out-degree histogram (fire-and-forget) + CSR position assignment (staged).
// fillc's final value == in-degree histogram (used by the scan for rowptr).
__global__ void deg_pos_k(const int* __restrict__ ei, int E, const int* __restrict__ flag,
                          int* __restrict__ deg, int* __restrict__ fillc,
                          int2* __restrict__ stage) {
  int e = blockIdx.x * 256 + threadIdx.x;
  if (e >= E) return;
  int sh = (*flag) ? 0 : 1;
  int s = ei[(size_t)e << sh];
  int d = ei[(size_t)(E + e) << sh];
  if ((unsigned)s >= (unsigned)N_NODES || (unsigned)d >= (unsigned)N_NODES || s == d) {
    stage[e] = make_int2(-1, 0);
    return;
  }
  atomicAdd(deg + s, 1);                 // no return needed
  int pos = atomicAdd(fillc + d, 1);
  stage[e] = make_int2(d, pos);
}

__global__ void dinv_k(const int* __restrict__ deg, float* __restrict__ dinv, int n) {
  int i = blockIdx.x * 256 + threadIdx.x;
  if (i >= n) return;
  int dg = deg[i];
  dinv[i] = dg > 0 ? rsqrtf((float)dg) : 0.f;
}

// K2: atomic-free CSR fill from the staged (d,pos) pairs.
__global__ void scatter_k(const int* __restrict__ ei, int E, const int* __restrict__ flag,
                          const float* __restrict__ dinv, const int* __restrict__ rowptr,
                          const int2* __restrict__ stage, int2* __restrict__ csr) {
  int e = blockIdx.x * 256 + threadIdx.x;
  if (e >= E) return;
  int2 st = stage[e];
  if (st.x < 0) return;
  int sh = (*flag) ? 0 : 1;
  int s = ei[(size_t)e << sh];
  float w = -dinv[s] * dinv[st.x];
  csr[rowptr[st.x] + st.y] = make_int2(s, __builtin_bit_cast(int, w));
}

// ---------------- scans (rowptr from cnt=fillc) ----------------

__global__ void scanA_k(const int* __restrict__ cnt, int* __restrict__ bsum, int nElem) {
  __shared__ int s[256];
  int b = blockIdx.x, t = threadIdx.x;
  int base = b * 1024;
  int sum = 0;
  for (int i = t; i < 1024; i += 256) {
    int idx = base + i;
    sum += (idx < nElem) ? cnt[idx] : 0;
  }
  s[t] = sum; __syncthreads();
  for (int off = 128; off > 0; off >>= 1) {
    if (t < off) s[t] += s[t + off];
    __syncthreads();
  }
  if (t == 0) bsum[b] = s[0];
}

__global__ void scanB_k(int* __restrict__ bsum, int* __restrict__ rowptrN, int nChunk) {
  __shared__ int s[128];
  int t = threadIdx.x;
  int v = (t < nChunk) ? bsum[t] : 0;
  s[t] = v; __syncthreads();
  for (int off = 1; off < 128; off <<= 1) {
    int x = (t >= off) ? s[t - off] : 0;
    __syncthreads();
    s[t] += x;
    __syncthreads();
  }
  int excl = s[t] - v;
  if (t < nChunk) bsum[t] = excl;
  if (t == 127) *rowptrN = s[127];
}

__global__ void scanC_k(const int* __restrict__ cnt, const int* __restrict__ bsum,
                        int* __restrict__ rowptr, int nElem) {
  __shared__ int s[256];
  int b = blockIdx.x, t = threadIdx.x;
  int base = b * 1024 + t * 4;
  int v[4]; int tot = 0;
  for (int i = 0; i < 4; i++) {
    int idx = base + i;
    v[i] = (idx < nElem) ? cnt[idx] : 0;
    tot += v[i];
  }
  s[t] = tot; __syncthreads();
  for (int off = 1; off < 256; off <<= 1) {
    int x = (t >= off) ? s[t - off] : 0;
    __syncthreads();
    s[t] += x;
    __syncthreads();
  }
  int excl = s[t] - tot + bsum[b];
  for (int i = 0; i < 4; i++) {
    int idx = base + i;
    if (idx < nElem) { rowptr[idx] = excl; excl += v[i]; }
  }
}

// ---------------- weight prep ----------------

// W (float): [3][Fin][128].  out (bf16): [384][Kp] = (W0-W2)^T | W1^T | (2W2)^T
__global__ void build_wct_k(const float* __restrict__ W, bf16* __restrict__ out, int Fin, int Kp) {
  int idx = blockIdx.x * 256 + threadIdx.x;
  if (idx >= 384 * Kp) return;
  int r = idx / Kp, k = idx % Kp;
  int t = r >> 7, j = r & 127;
  float v = 0.f;
  if (k < Fin) {
    if (t == 0)
      v = W[(size_t)k * 128 + j] - W[(size_t)2 * Fin * 128 + (size_t)k * 128 + j];
    else if (t == 1)
      v = W[(size_t)Fin * 128 + (size_t)k * 128 + j];
    else
      v = 2.f * W[(size_t)2 * Fin * 128 + (size_t)k * 128 + j];
  }
  out[(size_t)r * Kp + k] = (bf16)v;
}

// pad x (float [N][165]) -> xp (bf16 [N][192], zeros in 165..191)
__global__ void pad_x_k(const float* __restrict__ x, bf16* __restrict__ xp) {
  int idx = blockIdx.x * 256 + threadIdx.x;
  if (idx >= N_NODES * 192) return;
  int n = idx / 192, k = idx % 192;
  xp[idx] = (k < F_IN) ? (bf16)x[(size_t)n * F_IN + k] : (bf16)0.f;
}

// ---------------- GEMM: {C0,C1,C2}[M][128] = A[M][lda] @ Bt[y*128..][K]^T ----

__global__ __launch_bounds__(256) void gemm3_k(const bf16* __restrict__ A, int lda,
                                               const bf16* __restrict__ Bt, int K,
                                               bf16* __restrict__ C0, bf16* __restrict__ C1,
                                               bf16* __restrict__ C2, int M) {
  __shared__ __align__(16) bf16 As[128 * 32];
  __shared__ __align__(16) bf16 Bs[128 * 32];
  const int tid = threadIdx.x;
  const int w = tid >> 6, l = tid & 63;
  const int mBase = blockIdx.x * 128;
  const int nb = blockIdx.y * 128;
  const int wm = (w >> 1) * 64, wn = (w & 1) * 64;
  const int lr = l & 15, lq = l >> 4;
  f32x4 acc[4][4] = {};
  for (int k0 = 0; k0 < K; k0 += 32) {
#pragma unroll
    for (int p = 0; p < 2; ++p) {
      int q = w * 2 + p;
      int row = q * 16 + (l >> 2);
      int seg = (l & 3) * 8;
      int ar = mBase + row; if (ar > M - 1) ar = M - 1;  // clamp: no OOB reads
      async16(A + (size_t)ar * lda + k0 + seg, &As[q * 512]);
      async16(Bt + (size_t)(nb + row) * K + k0 + seg, &Bs[q * 512]);
    }
    __syncthreads();
    bf16x8 a[4], b[4];
#pragma unroll
    for (int i = 0; i < 4; i++) a[i] = *(const bf16x8*)&As[(wm + i * 16 + lr) * 32 + lq * 8];
#pragma unroll
    for (int j = 0; j < 4; j++) b[j] = *(const bf16x8*)&Bs[(wn + j * 16 + lr) * 32 + lq * 8];
#pragma unroll
    for (int i = 0; i < 4; i++)
#pragma unroll
      for (int j = 0; j < 4; j++)
        acc[i][j] = __builtin_amdgcn_mfma_f32_16x16x32_bf16(a[i], b[j], acc[i][j], 0, 0, 0);
    __syncthreads();
  }
  bf16* __restrict__ C = (blockIdx.y == 0) ? C0 : ((blockIdx.y == 1) ? C1 : C2);
#pragma unroll
  for (int i = 0; i < 4; i++) {
#pragma unroll
    for (int r = 0; r < 4; r++) {
      int row = mBase + wm + i * 16 + lq * 4 + r;
      if (row < M) {
#pragma unroll
        for (int j = 0; j < 4; j++) {
          int col = wn + j * 16 + lr;
          C[(size_t)row * 128 + col] = (bf16)acc[i][j][r];
        }
      }
    }
  }
}

// ---------------- sparse propagation (latency-optimized) ----------------
// One wave per node. Half-wave per edge slot; 16 edges per loop body
// (8 csr loads + 8 gathers in flight per half). Lane covers 4 features.
// MODE 0: out[n] = P(gsrc)[n] + addA[n]                        (bf16)
// MODE 1: out[n] = relu(P(gsrc)[n] + addA[n] + bias)           (bf16)
// MODE 2: v = P(gsrc)[n] + addA[n] + addB[n] + bias;
//         fout[n*2..] = log_softmax(v @ Wl + bl)               (float32)
template <int MODE>
__global__ __launch_bounds__(256) void prop_k(const int* __restrict__ rowptr,
                                              const int2* __restrict__ csr,
                                              const bf16* __restrict__ gsrc,
                                              const bf16* __restrict__ addA,
                                              const bf16* __restrict__ addB,
                                              const float* __restrict__ bias,
                                              const float* __restrict__ Wl,
                                              const float* __restrict__ bl,
                                              bf16* __restrict__ out,
                                              float* __restrict__ fout) {
  const int n = blockIdx.x * 4 + (threadIdx.x >> 6);
  const int c = threadIdx.x & 63;
  const int half = c >> 5, lc = c & 31;
  const int beg = rowptr[n], end = rowptr[n + 1];
  const bf16* __restrict__ gl = gsrc + lc * 4;  // lane-fixed feature offset

  float a0 = 0.f, a1 = 0.f, a2 = 0.f, a3 = 0.f;
  for (int e0 = beg; e0 < end; e0 += 16) {
    int2 sw[8];
    float wv[8];
    uint2 g[8];
#pragma unroll
    for (int k = 0; k < 8; k++) {
      int idx = e0 + 2 * k + half;
      bool valid = idx < end;
      sw[k] = csr[valid ? idx : beg];
      wv[k] = valid ? __builtin_bit_cast(float, sw[k].y) : 0.f;
    }
#pragma unroll
    for (int k = 0; k < 8; k++) g[k] = *(const uint2*)(gl + (size_t)sw[k].x * 128);
#pragma unroll
    for (int k = 0; k < 8; k++) {
      a0 += wv[k] * bfu(g[k].x & 0xffffu);
      a1 += wv[k] * bfu(g[k].x >> 16);
      a2 += wv[k] * bfu(g[k].y & 0xffffu);
      a3 += wv[k] * bfu(g[k].y >> 16);
    }
  }

  if (MODE == 2) {
    if (half == 0) {
      uint2 ua = *(const uint2*)(addA + (size_t)n * 128 + lc * 4);
      uint2 uh = *(const uint2*)(addB + (size_t)n * 128 + lc * 4);
      a0 += bfu(ua.x & 0xffffu) + bfu(uh.x & 0xffffu) + bias[4 * lc + 0];
      a1 += bfu(ua.x >> 16) + bfu(uh.x >> 16) + bias[4 * lc + 1];
      a2 += bfu(ua.y & 0xffffu) + bfu(uh.y & 0xffffu) + bias[4 * lc + 2];
      a3 += bfu(ua.y >> 16) + bfu(uh.y >> 16) + bias[4 * lc + 3];
    }
    float z0 = a0 * Wl[(4 * lc + 0) * 2] + a1 * Wl[(4 * lc + 1) * 2] +
               a2 * Wl[(4 * lc + 2) * 2] + a3 * Wl[(4 * lc + 3) * 2];
    float z1 = a0 * Wl[(4 * lc + 0) * 2 + 1] + a1 * Wl[(4 * lc + 1) * 2 + 1] +
               a2 * Wl[(4 * lc + 2) * 2 + 1] + a3 * Wl[(4 * lc + 3) * 2 + 1];
#pragma unroll
    for (int off = 32; off > 0; off >>= 1) {
      z0 += __shfl_down(z0, off);
      z1 += __shfl_down(z1, off);
    }
    if (c == 0) {
      z0 += bl[0];
      z1 += bl[1];
      float m = fmaxf(z0, z1);
      float lse = m + logf(expf(z0 - m) + expf(z1 - m));
      fout[(size_t)n * 2 + 0] = z0 - lse;
      fout[(size_t)n * 2 + 1] = z1 - lse;
    }
  } else {
    a0 += __shfl_down(a0, 32);
    a1 += __shfl_down(a1, 32);
    a2 += __shfl_down(a2, 32);
    a3 += __shfl_down(a3, 32);
    if (half == 0) {
      uint2 ua = *(const uint2*)(addA + (size_t)n * 128 + lc * 4);
      a0 += bfu(ua.x & 0xffffu);
      a1 += bfu(ua.x >> 16);
      a2 += bfu(ua.y & 0xffffu);
      a3 += bfu(ua.y >> 16);
      if (MODE == 1) {
        a0 = fmaxf(a0 + bias[4 * lc + 0], 0.f);
        a1 = fmaxf(a1 + bias[4 * lc + 1], 0.f);
        a2 = fmaxf(a2 + bias[4 * lc + 2], 0.f);
        a3 = fmaxf(a3 + bias[4 * lc + 3], 0.f);
      }
      uint2 st;
      st.x = packbf2(a0, a1);
      st.y = packbf2(a2, a3);
      *(uint2*)(out + (size_t)n * 128 + lc * 4) = st;
    }
  }
}

// edges -> float32 output region
__global__ void copy_edges_k(const int* __restrict__ ei, const int* __restrict__ flag,
                             float* __restrict__ out, int n) {
  int i = blockIdx.x * 256 + threadIdx.x;
  if (i >= n) return;
  int sh = (*flag) ? 0 : 1;
  out[i] = (float)ei[(size_t)i << sh];
}

// ---------------- launch ----------------

extern "C" void kernel_launch(void* const* d_in, const int* in_sizes, int n_in,
                              void* d_out, int out_size, void* d_ws, size_t ws_size,
                              hipStream_t stream) {
  const float* x = (const float*)d_in[0];
  const int* ei = (const int*)d_in[1];
  const float* W1 = (const float*)d_in[2];
  const float* b1 = (const float*)d_in[3];
  const float* W2 = (const float*)d_in[4];
  const float* b2 = (const float*)d_in[5];
  const float* Wl = (const float*)d_in[6];
  const float* bl = (const float*)d_in[7];
  float* outp = (float*)d_out;   // d_out is FLOAT32 (reference output dtype)

  const int N = N_NODES;
  const int E = in_sizes[1] / 2;
  const int nChunk = cdiv(N, 1024);  // 98

  char* ws = (char*)d_ws;
  size_t off = 0;
  auto alloc = [&](size_t bytes) {
    off = (off + 255) & ~(size_t)255;
    size_t o = off;
    off += bytes;
    return o;
  };
  size_t o_z = alloc((size_t)(2 * N + 1) * 4);  // deg | cnt(=fillc) | flag — one memset
  int* deg = (int*)(ws + o_z);
  int* cnt = deg + N;
  int* flag = cnt + N;
  int* rowptr = (int*)(ws + alloc((size_t)(N + 1) * 4));
  int* bsum = (int*)(ws + alloc(512));
  float* dinv = (float*)(ws + alloc((size_t)N * 4));
  int2* stage = (int2*)(ws + alloc((size_t)E * 8));
  int2* csr = (int2*)(ws + alloc((size_t)E * 8));
  bf16* wct1 = (bf16*)(ws + alloc((size_t)384 * 192 * 2));
  bf16* wct2 = (bf16*)(ws + alloc((size_t)384 * 128 * 2));
  bf16* xp = (bf16*)(ws + alloc((size_t)N * 192 * 2));  // X0 = first N*128 of this
  bf16* X0 = xp;
  bf16* U0 = (bf16*)(ws + alloc((size_t)N * 128 * 2));
  bf16* U1 = (bf16*)(ws + alloc((size_t)N * 128 * 2));
  bf16* U2 = (bf16*)(ws + alloc((size_t)N * 128 * 2));
  (void)ws_size;  // total ≈ 143 MB

  hipMemsetAsync(deg, 0, (size_t)(2 * N + 1) * 4, stream);

  detect_k<<<256, 256, 0, stream>>>(ei, flag);
  deg_pos_k<<<cdiv(E, 256), 256, 0, stream>>>(ei, E, flag, deg, cnt, stage);
  dinv_k<<<cdiv(N, 256), 256, 0, stream>>>(deg, dinv, N);
  scanA_k<<<nChunk, 256, 0, stream>>>(cnt, bsum, N);
  scanB_k<<<1, 128, 0, stream>>>(bsum, rowptr + N, nChunk);
  scanC_k<<<nChunk, 256, 0, stream>>>(cnt, bsum, rowptr, N);
  scatter_k<<<cdiv(E, 256), 256, 0, stream>>>(ei, E, flag, dinv, rowptr, stage, csr);

  pad_x_k<<<cdiv(N * 192, 256), 256, 0, stream>>>(x, xp);
  build_wct_k<<<cdiv(384 * 192, 256), 256, 0, stream>>>(W1, wct1, F_IN, 192);
  build_wct_k<<<cdiv(384 * 128, 256), 256, 0, stream>>>(W2, wct2, 128, 128);

  const int gm = cdiv(N, 128);
  // ----- layer 1: Y0 -> U0, Y1 -> U1, Y2 -> U2 (one merged launch) -----
  gemm3_k<<<dim3(gm, 3), 256, 0, stream>>>(xp, 192, wct1, 192, U0, U1, U2, N);
  // A1 = P(Y2) + Y1  (gather U2, own-row U1 -> U1)
  prop_k<0><<<N / 4, 256, 0, stream>>>(rowptr, csr, U2, U1, nullptr, nullptr, nullptr, nullptr, U1, nullptr);
  // h = relu(P(A1) + Y0 + b1)  (gather U1, own-row U0 -> U0)
  prop_k<1><<<N / 4, 256, 0, stream>>>(rowptr, csr, U1, U0, nullptr, b1, nullptr, nullptr, U0, nullptr);
  // ----- layer 2 from h=U0: Z0 -> X0, Z1 -> U1, Z2 -> U2 -----
  gemm3_k<<<dim3(gm, 3), 256, 0, stream>>>(U0, 128, wct2, 128, X0, U1, U2, N);
  // A2 = P(Z2) + Z1  (gather U2, own-row U1 -> U1)
  prop_k<0><<<N / 4, 256, 0, stream>>>(rowptr, csr, U2, U1, nullptr, nullptr, nullptr, nullptr, U1, nullptr);
  // logits(float32) = log_softmax((P(A2) + Z0 + h + b2) @ Wl + bl) -> outp[0:2N)
  prop_k<2><<<N / 4, 256, 0, stream>>>(rowptr, csr, U1, X0, U0, b2, Wl, bl, nullptr, outp);

  // edges (float32) -> outp[2N : 2N+2E)
  copy_edges_k<<<cdiv(2 * E, 256), 256, 0, stream>>>(ei, flag, outp + (size_t)2 * N, 2 * E);
}